// Round 8
// baseline (67.072 us; speedup 1.0000x reference)
//
#include <hip/hip_runtime.h>
#include <hip/hip_bf16.h>
#include <hip/hip_fp16.h>
#include <math.h>

#define NODE_DIM 128
#define HIDDEN   64
#define N_NODES  100000
#define N_RELS   50
#define N_EDGESC 1000000
#define TEMPERATURE 0.5f
#define BIASF 0.0001f

typedef __attribute__((ext_vector_type(8))) _Float16 f16x8;
typedef __attribute__((ext_vector_type(2))) _Float16 hv2;
typedef __attribute__((ext_vector_type(4))) float    f32x4;

union U4 { uint4 u; hv2 h[4]; };   // 16 bytes: 4 x hv2 (8 halves)

// ---------------------------------------------------------------------------
// Kernel 1 (tiny): blocks 0..95 convert W1_{con,src,dst} f32 [128][64] into
// wt f16 [n=192][k=128] transposed + XOR-swizzled (k ^= (n&7)<<3) so the GEMM
// can global_load_lds it linearly and ds_read_b128 conflict-free.
// Blocks 96..: per-relation qh[r][64] = fp16(rel_r @ W1_con + b1_con) and
// srel[r] = MLP_edge(rel_r) + b2_edge + b2_con.  Block 96 lanes<64 also write
// w2h = fp16(W2_con).
// ---------------------------------------------------------------------------
__global__ __launch_bounds__(256) void prep_small(
    const float* __restrict__ W1c, const float* __restrict__ W1s,
    const float* __restrict__ W1d,
    const float* __restrict__ rel_emb,
    const float* __restrict__ b1c,
    const float* __restrict__ W1e, const float* __restrict__ b1e,
    const float* __restrict__ W2e, const float* __restrict__ b2e,
    const float* __restrict__ b2c, const float* __restrict__ W2c,
    _Float16* __restrict__ wt,
    _Float16* __restrict__ qh, float* __restrict__ srel,
    _Float16* __restrict__ w2h) {
  const int bid = blockIdx.x;
  if (bid < 96) {
    const int tid = bid * 256 + threadIdx.x;     // 0..24575
    const int k = tid / 192;
    const int n = tid % 192;
    const float* W = (n < 64) ? W1c : (n < 128) ? W1s : W1d;
    const float v = W[k * HIDDEN + (n & 63)];
    const int ks = k ^ ((n & 7) << 3);
    wt[n * NODE_DIM + ks] = (_Float16)v;
  } else {
    if (bid == 96 && threadIdx.x < HIDDEN)
      w2h[threadIdx.x] = (_Float16)W2c[threadIdx.x];
    const int r = (bid - 96) * 4 + (threadIdx.x >> 6);
    const int l = threadIdx.x & 63;
    if (r >= N_RELS) return;
    const float* x = rel_emb + (size_t)r * NODE_DIM;
    float ac = 0.f, ae = 0.f;
    #pragma unroll 8
    for (int k = 0; k < NODE_DIM; ++k) {
      float xk = x[k];
      ac = fmaf(xk, W1c[k * HIDDEN + l], ac);
      ae = fmaf(xk, W1e[k * HIDDEN + l], ae);
    }
    qh[r * HIDDEN + l] = (_Float16)(ac + b1c[l]);
    float he = fmaxf(ae + b1e[l], 0.f) * W2e[l];
    #pragma unroll
    for (int off = 32; off > 0; off >>= 1) he += __shfl_xor(he, off);
    if (l == 0) srel[r] = he + b2e[0] + b2c[0];
  }
}

// ---------------------------------------------------------------------------
// Kernel 2: MFMA prep GEMM.  C[100000 x 192] = all_embed @ [W1c|W1s|W1d].
// Block = 8 waves, BM=128 (wave w -> rows m0..m0+15). K=128 via 4 MFMA steps.
// Cols 0..63 -> pcon (fp16, bias folded into qh); 64..127 -> fused
// relu(.+b1s)@W2s+b2s -> ssrc; 128..191 -> sdst.
// ---------------------------------------------------------------------------
__global__ __launch_bounds__(512) void prep_gemm(
    const float* __restrict__ x,
    const _Float16* __restrict__ wt,      // [192][128] f16, k XOR-swizzled
    const float* __restrict__ b1s, const float* __restrict__ W2s,
    const float* __restrict__ b2s,
    const float* __restrict__ b1d, const float* __restrict__ W2d,
    const float* __restrict__ b2d,
    __half* __restrict__ pcon,
    float* __restrict__ ssrc, float* __restrict__ sdst) {
  __shared__ _Float16 bl[192 * NODE_DIM];       // 48 KiB
  const int wv = threadIdx.x >> 6;              // 0..7
  const int l  = threadIdx.x & 63;
  const int hi = l >> 4;
  const int c  = l & 15;

  {
    const char* g = (const char*)wt;
    #pragma unroll
    for (int i = 0; i < 6; ++i) {
      const int chunk = (i * 8 + wv) << 10;
      __builtin_amdgcn_global_load_lds(
          (const __attribute__((address_space(1))) void*)(g + chunk + l * 16),
          (__attribute__((address_space(3))) void*)((char*)bl + chunk),
          16, 0, 0);
    }
  }

  const int m0   = blockIdx.x * 128 + wv * 16;
  const int arow = m0 + c;
  const int rowc = arow < N_NODES ? arow : N_NODES - 1;
  const float* xr = x + (size_t)rowc * NODE_DIM + hi * 8;
  f16x8 a[4];
  #pragma unroll
  for (int s = 0; s < 4; ++s) {
    float4 u0 = *(const float4*)(xr + s * 32);
    float4 u1 = *(const float4*)(xr + s * 32 + 4);
    f16x8 av;
    av[0] = (_Float16)u0.x; av[1] = (_Float16)u0.y;
    av[2] = (_Float16)u0.z; av[3] = (_Float16)u0.w;
    av[4] = (_Float16)u1.x; av[5] = (_Float16)u1.y;
    av[6] = (_Float16)u1.z; av[7] = (_Float16)u1.w;
    a[s] = av;
  }

  __syncthreads();

  f32x4 acc[12];
  #pragma unroll
  for (int i = 0; i < 12; ++i) acc[i] = (f32x4){0.f, 0.f, 0.f, 0.f};

  #pragma unroll
  for (int tt = 0; tt < 12; ++tt) {
    const int n = tt * 16 + c;
    const int nbase = n * NODE_DIM;
    #pragma unroll
    for (int s = 0; s < 4; ++s) {
      const int ks = (s * 32 + hi * 8) ^ ((n & 7) << 3);
      f16x8 b = *(const f16x8*)(&bl[nbase + ks]);
      acc[tt] = __builtin_amdgcn_mfma_f32_16x16x32_f16(a[s], b, acc[tt], 0, 0, 0);
    }
  }

  #pragma unroll
  for (int tt = 0; tt < 4; ++tt) {
    #pragma unroll
    for (int g = 0; g < 4; ++g) {
      const int row = m0 + hi * 4 + g;
      if (row < N_NODES)
        pcon[(size_t)row * HIDDEN + tt * 16 + c] = __float2half(acc[tt][g]);
    }
  }
  float ps[4] = {0.f, 0.f, 0.f, 0.f};
  float pd[4] = {0.f, 0.f, 0.f, 0.f};
  #pragma unroll
  for (int tt = 0; tt < 4; ++tt) {
    const int h = tt * 16 + c;
    const float b1sv = b1s[h], w2sv = W2s[h];
    const float b1dv = b1d[h], w2dv = W2d[h];
    #pragma unroll
    for (int g = 0; g < 4; ++g) {
      ps[g] += fmaxf(acc[4 + tt][g] + b1sv, 0.f) * w2sv;
      pd[g] += fmaxf(acc[8 + tt][g] + b1dv, 0.f) * w2dv;
    }
  }
  #pragma unroll
  for (int off = 1; off < 16; off <<= 1) {
    #pragma unroll
    for (int g = 0; g < 4; ++g) {
      ps[g] += __shfl_xor(ps[g], off);
      pd[g] += __shfl_xor(pd[g], off);
    }
  }
  if (c == 0) {
    const float bs = b2s[0], bd = b2d[0];
    #pragma unroll
    for (int g = 0; g < 4; ++g) {
      const int row = m0 + hi * 4 + g;
      if (row < N_NODES) { ssrc[row] = ps[g] + bs; sdst[row] = pd[g] + bd; }
    }
  }
}

// ---------------------------------------------------------------------------
// Edge kernel: 4 lanes per EDGE-PAIR (2 edges per group). Lane sub loads
// chunks sub and sub+4 of both endpoint rows of BOTH edges -> 8 random b128
// per lane in flight (2x round 7), still 64B-line coalesced per instruction.
// Tail on lanes sub<2 (one edge each): scalar gathers + transcendentals.
// ---------------------------------------------------------------------------
__global__ __launch_bounds__(256) void edge_kernel(
    const int*   __restrict__ edge_index,
    const int*   __restrict__ edge_type,
    const float* __restrict__ u,
    const _Float16* __restrict__ pcon,
    const float* __restrict__ ssrc,
    const float* __restrict__ sdst,
    const _Float16* __restrict__ qh,
    const float* __restrict__ srel,
    const _Float16* __restrict__ w2h,
    float* __restrict__ out) {
  const int tid = blockIdx.x * 256 + threadIdx.x;
  const int p   = tid >> 2;               // pair index
  const int sub = tid & 3;
  if (p >= N_EDGESC / 2) return;
  const int eA = 2 * p;
  const int eB = eA + 1;

  const int srcA = edge_index[eA];
  const int srcB = edge_index[eB];
  const int dstA = edge_index[N_EDGESC + eA];
  const int dstB = edge_index[N_EDGESC + eB];
  const int rA   = edge_type[eA];
  const int rB   = edge_type[eB];

  const uint4* SA = (const uint4*)(pcon + srcA * HIDDEN);   // 8 x uint4 per row
  const uint4* SB = (const uint4*)(pcon + srcB * HIDDEN);
  const uint4* DA = (const uint4*)(pcon + dstA * HIDDEN);
  const uint4* DB = (const uint4*)(pcon + dstB * HIDDEN);
  const uint4* QA = (const uint4*)(qh + rA * HIDDEN);
  const uint4* QB = (const uint4*)(qh + rB * HIDDEN);
  const uint4* Wp = (const uint4*)w2h;

  U4 sA0, sA1, dA0, dA1, sB0, sB1, dB0, dB1, qA0, qA1, qB0, qB1, w0, w1;
  sA0.u = SA[sub];  sA1.u = SA[sub + 4];
  dA0.u = DA[sub];  dA1.u = DA[sub + 4];
  sB0.u = SB[sub];  sB1.u = SB[sub + 4];
  dB0.u = DB[sub];  dB1.u = DB[sub + 4];
  qA0.u = QA[sub];  qA1.u = QA[sub + 4];
  qB0.u = QB[sub];  qB1.u = QB[sub + 4];
  w0.u  = Wp[sub];  w1.u  = Wp[sub + 4];

  float accA = 0.f, accB = 0.f;
  #pragma unroll
  for (int j = 0; j < 4; ++j) {
    hv2 hA0 = sA0.h[j] + dA0.h[j] + qA0.h[j];
    hA0 = __builtin_elementwise_max(hA0, (hv2)(_Float16)0.f);
    accA = __builtin_amdgcn_fdot2(hA0, w0.h[j], accA, false);
    hv2 hA1 = sA1.h[j] + dA1.h[j] + qA1.h[j];
    hA1 = __builtin_elementwise_max(hA1, (hv2)(_Float16)0.f);
    accA = __builtin_amdgcn_fdot2(hA1, w1.h[j], accA, false);
    hv2 hB0 = sB0.h[j] + dB0.h[j] + qB0.h[j];
    hB0 = __builtin_elementwise_max(hB0, (hv2)(_Float16)0.f);
    accB = __builtin_amdgcn_fdot2(hB0, w0.h[j], accB, false);
    hv2 hB1 = sB1.h[j] + dB1.h[j] + qB1.h[j];
    hB1 = __builtin_elementwise_max(hB1, (hv2)(_Float16)0.f);
    accB = __builtin_amdgcn_fdot2(hB1, w1.h[j], accB, false);
  }
  accA += __shfl_xor(accA, 1);
  accA += __shfl_xor(accA, 2);
  accB += __shfl_xor(accB, 1);
  accB += __shfl_xor(accB, 2);

  if (sub < 2) {
    const int   e   = eA + sub;
    const float acc = (sub == 0) ? accA : accB;
    const int   s   = (sub == 0) ? srcA : srcB;
    const int   d   = (sub == 0) ? dstA : dstB;
    const int   rr  = (sub == 0) ? rA   : rB;
    const float wsum = acc + ssrc[s] + sdst[d] + srel[rr];
    const float uu   = u[e];
    const float eps  = fmaf(2.f * BIASF - 1.f, uu, 1.f - BIASF);   // eps
    const float ome  = fmaf(1.f - 2.f * BIASF, uu, BIASF);         // 1 - eps
    const float g    = __logf(eps) - __logf(ome);
    const float z    = (g + wsum) * (1.f / TEMPERATURE);
    out[e] = __builtin_amdgcn_rcpf(1.f + __expf(-z));
  }
}

extern "C" void kernel_launch(void* const* d_in, const int* in_sizes, int n_in,
                              void* d_out, int out_size, void* d_ws, size_t ws_size,
                              hipStream_t stream) {
  const int*   edge_index = (const int*)d_in[0];
  const int*   edge_type  = (const int*)d_in[1];
  const float* all_embed  = (const float*)d_in[2];
  const float* rel_emb    = (const float*)d_in[3];
  const float* u          = (const float*)d_in[4];
  const float* W1_src = (const float*)d_in[5];
  const float* b1_src = (const float*)d_in[6];
  const float* W2_src = (const float*)d_in[7];
  const float* b2_src = (const float*)d_in[8];
  const float* W1_dst = (const float*)d_in[9];
  const float* b1_dst = (const float*)d_in[10];
  const float* W2_dst = (const float*)d_in[11];
  const float* b2_dst = (const float*)d_in[12];
  const float* W1_edge = (const float*)d_in[13];
  const float* b1_edge = (const float*)d_in[14];
  const float* W2_edge = (const float*)d_in[15];
  const float* b2_edge = (const float*)d_in[16];
  const float* W1_con = (const float*)d_in[17];
  const float* b1_con = (const float*)d_in[18];
  const float* W2_con = (const float*)d_in[19];
  const float* b2_con = (const float*)d_in[20];

  // Workspace layout (all fp16 tables 16B-aligned):
  char* ws = (char*)d_ws;
  _Float16* pcon = (_Float16*)ws;                                 // 12,800,000 B
  float*    ssrc = (float*)(ws + (size_t)N_NODES * HIDDEN * 2);   // +400,000 B
  float*    sdst = ssrc + N_NODES;                                // +400,000 B
  _Float16* wt   = (_Float16*)(sdst + N_NODES);                   // 49,152 B (16B-aligned)
  _Float16* qh   = wt + 192 * NODE_DIM;                           // 6,400 B (16B-aligned)
  _Float16* w2h  = qh + N_RELS * HIDDEN;                          // 128 B (16B-aligned)
  float*    srel = (float*)(w2h + HIDDEN);                        // 200 B

  prep_small<<<96 + (N_RELS + 3) / 4, 256, 0, stream>>>(
      W1_con, W1_src, W1_dst, rel_emb, b1_con,
      W1_edge, b1_edge, W2_edge, b2_edge, b2_con, W2_con,
      wt, qh, srel, w2h);

  prep_gemm<<<(N_NODES + 127) / 128, 512, 0, stream>>>(
      all_embed, wt,
      b1_src, W2_src, b2_src, b1_dst, W2_dst, b2_dst,
      (__half*)pcon, ssrc, sdst);

  const int groups = (N_EDGESC / 2) * 4;               // 4 lanes per pair
  edge_kernel<<<(groups + 255) / 256, 256, 0, stream>>>(
      edge_index, edge_type, u, pcon, ssrc, sdst, qh, srel, w2h,
      (float*)d_out);
}

// Round 9
// 64.508 us; speedup vs baseline: 1.0397x; 1.0397x over previous
//
#include <hip/hip_runtime.h>
#include <hip/hip_bf16.h>
#include <hip/hip_fp16.h>
#include <math.h>

#define NODE_DIM 128
#define HIDDEN   64
#define N_NODES  100000
#define N_RELS   50
#define N_EDGESC 1000000
#define TEMPERATURE 0.5f
#define BIASF 0.0001f
#define NBLK_GEMM ((N_NODES + 127) / 128)   // 782

typedef __attribute__((ext_vector_type(8))) _Float16 f16x8;
typedef __attribute__((ext_vector_type(2))) _Float16 hv2;
typedef __attribute__((ext_vector_type(4))) float    f32x4;

union U4 { uint4 u; hv2 h[4]; };   // 16 bytes: 4 x hv2 (8 halves)

// ---------------------------------------------------------------------------
// Kernel 1 (tiny, 96 blocks): convert W1_{con,src,dst} f32 [128][64] into
// wt f16 [n=192][k=128] transposed + XOR-swizzled (k ^= (n&7)<<3) so the GEMM
// can global_load_lds it linearly and ds_read_b128 conflict-free.
// ---------------------------------------------------------------------------
__global__ __launch_bounds__(256) void prep_small(
    const float* __restrict__ W1c, const float* __restrict__ W1s,
    const float* __restrict__ W1d,
    _Float16* __restrict__ wt) {
  const int tid = blockIdx.x * 256 + threadIdx.x;     // 0..24575
  const int k = tid / 192;
  const int n = tid % 192;
  const float* W = (n < 64) ? W1c : (n < 128) ? W1s : W1d;
  const float v = W[k * HIDDEN + (n & 63)];
  const int ks = k ^ ((n & 7) << 3);
  wt[n * NODE_DIM + ks] = (_Float16)v;
}

// ---------------------------------------------------------------------------
// Kernel 2: MFMA prep GEMM.  C[100000 x 192] = all_embed @ [W1c|W1s|W1d].
// Blocks 0..781: 8 waves, BM=128. Cols 0..63 -> pcon (fp16, bias folded into
// qh); 64..127 -> fused relu(.+b1s)@W2s+b2s -> ssrc; 128..191 -> sdst.
// Blocks 782.. (tail): per-relation qh[r] = fp16(rel_r @ W1_con + b1_con),
// srel[r] = MLP_edge(rel_r)+b2_edge+b2_con, plus w2h = fp16(W2_con).
// ---------------------------------------------------------------------------
__global__ __launch_bounds__(512) void prep_gemm(
    const float* __restrict__ x,
    const _Float16* __restrict__ wt,      // [192][128] f16, k XOR-swizzled
    const float* __restrict__ b1s, const float* __restrict__ W2s,
    const float* __restrict__ b2s,
    const float* __restrict__ b1d, const float* __restrict__ W2d,
    const float* __restrict__ b2d,
    const float* __restrict__ rel_emb,
    const float* __restrict__ W1c, const float* __restrict__ b1c,
    const float* __restrict__ W1e, const float* __restrict__ b1e,
    const float* __restrict__ W2e, const float* __restrict__ b2e,
    const float* __restrict__ b2c, const float* __restrict__ W2c,
    __half* __restrict__ pcon,
    float* __restrict__ ssrc, float* __restrict__ sdst,
    _Float16* __restrict__ qh, float* __restrict__ srel,
    _Float16* __restrict__ w2h) {
  const int wv = threadIdx.x >> 6;              // 0..7
  const int l  = threadIdx.x & 63;

  if (blockIdx.x >= NBLK_GEMM) {
    // ---- relation tail blocks (no LDS, no barriers) ----
    if (blockIdx.x == NBLK_GEMM && threadIdx.x < HIDDEN)
      w2h[threadIdx.x] = (_Float16)W2c[threadIdx.x];
    const int r = (blockIdx.x - NBLK_GEMM) * 8 + wv;
    if (r >= N_RELS) return;
    const float* xr = rel_emb + (size_t)r * NODE_DIM;
    float ac = 0.f, ae = 0.f;
    #pragma unroll 8
    for (int k = 0; k < NODE_DIM; ++k) {
      float xk = xr[k];
      ac = fmaf(xk, W1c[k * HIDDEN + l], ac);
      ae = fmaf(xk, W1e[k * HIDDEN + l], ae);
    }
    qh[r * HIDDEN + l] = (_Float16)(ac + b1c[l]);
    float he = fmaxf(ae + b1e[l], 0.f) * W2e[l];
    #pragma unroll
    for (int off = 32; off > 0; off >>= 1) he += __shfl_xor(he, off);
    if (l == 0) srel[r] = he + b2e[0] + b2c[0];
    return;
  }

  __shared__ _Float16 bl[192 * NODE_DIM];       // 48 KiB
  const int hi = l >> 4;
  const int c  = l & 15;

  {
    const char* g = (const char*)wt;
    #pragma unroll
    for (int i = 0; i < 6; ++i) {
      const int chunk = (i * 8 + wv) << 10;
      __builtin_amdgcn_global_load_lds(
          (const __attribute__((address_space(1))) void*)(g + chunk + l * 16),
          (__attribute__((address_space(3))) void*)((char*)bl + chunk),
          16, 0, 0);
    }
  }

  const int m0   = blockIdx.x * 128 + wv * 16;
  const int arow = m0 + c;
  const int rowc = arow < N_NODES ? arow : N_NODES - 1;
  const float* xr = x + (size_t)rowc * NODE_DIM + hi * 8;
  f16x8 a[4];
  #pragma unroll
  for (int s = 0; s < 4; ++s) {
    float4 u0 = *(const float4*)(xr + s * 32);
    float4 u1 = *(const float4*)(xr + s * 32 + 4);
    f16x8 av;
    av[0] = (_Float16)u0.x; av[1] = (_Float16)u0.y;
    av[2] = (_Float16)u0.z; av[3] = (_Float16)u0.w;
    av[4] = (_Float16)u1.x; av[5] = (_Float16)u1.y;
    av[6] = (_Float16)u1.z; av[7] = (_Float16)u1.w;
    a[s] = av;
  }

  __syncthreads();

  f32x4 acc[12];
  #pragma unroll
  for (int i = 0; i < 12; ++i) acc[i] = (f32x4){0.f, 0.f, 0.f, 0.f};

  #pragma unroll
  for (int tt = 0; tt < 12; ++tt) {
    const int n = tt * 16 + c;
    const int nbase = n * NODE_DIM;
    #pragma unroll
    for (int s = 0; s < 4; ++s) {
      const int ks = (s * 32 + hi * 8) ^ ((n & 7) << 3);
      f16x8 b = *(const f16x8*)(&bl[nbase + ks]);
      acc[tt] = __builtin_amdgcn_mfma_f32_16x16x32_f16(a[s], b, acc[tt], 0, 0, 0);
    }
  }

  #pragma unroll
  for (int tt = 0; tt < 4; ++tt) {
    #pragma unroll
    for (int g = 0; g < 4; ++g) {
      const int row = m0 + hi * 4 + g;
      if (row < N_NODES)
        pcon[(size_t)row * HIDDEN + tt * 16 + c] = __float2half(acc[tt][g]);
    }
  }
  float ps[4] = {0.f, 0.f, 0.f, 0.f};
  float pd[4] = {0.f, 0.f, 0.f, 0.f};
  #pragma unroll
  for (int tt = 0; tt < 4; ++tt) {
    const int h = tt * 16 + c;
    const float b1sv = b1s[h], w2sv = W2s[h];
    const float b1dv = b1d[h], w2dv = W2d[h];
    #pragma unroll
    for (int g = 0; g < 4; ++g) {
      ps[g] += fmaxf(acc[4 + tt][g] + b1sv, 0.f) * w2sv;
      pd[g] += fmaxf(acc[8 + tt][g] + b1dv, 0.f) * w2dv;
    }
  }
  #pragma unroll
  for (int off = 1; off < 16; off <<= 1) {
    #pragma unroll
    for (int g = 0; g < 4; ++g) {
      ps[g] += __shfl_xor(ps[g], off);
      pd[g] += __shfl_xor(pd[g], off);
    }
  }
  if (c == 0) {
    const float bs = b2s[0], bd = b2d[0];
    #pragma unroll
    for (int g = 0; g < 4; ++g) {
      const int row = m0 + hi * 4 + g;
      if (row < N_NODES) { ssrc[row] = ps[g] + bs; sdst[row] = pd[g] + bd; }
    }
  }
}

// ---------------------------------------------------------------------------
// Edge kernel (round-7 version, best measured): FOUR lanes per edge. Lane sub
// loads row chunks sub and sub+4 of both endpoint rows -> 4 random b128 per
// lane, coalesced into 64B lines per instruction. 16 edges/wave, 2-round
// shfl_xor reduce, tail at sub==0.
// ---------------------------------------------------------------------------
__global__ __launch_bounds__(256) void edge_kernel(
    const int*   __restrict__ edge_index,
    const int*   __restrict__ edge_type,
    const float* __restrict__ u,
    const _Float16* __restrict__ pcon,
    const float* __restrict__ ssrc,
    const float* __restrict__ sdst,
    const _Float16* __restrict__ qh,
    const float* __restrict__ srel,
    const _Float16* __restrict__ w2h,
    float* __restrict__ out) {
  const int tid = blockIdx.x * 256 + threadIdx.x;   // 4,000,000 exactly
  const int e   = tid >> 2;
  const int sub = tid & 3;

  const int src = edge_index[e];
  const int dst = edge_index[N_EDGESC + e];
  const int r   = edge_type[e];

  const uint4* Sp = (const uint4*)(pcon + src * HIDDEN);   // 8 x uint4 per row
  const uint4* Dp = (const uint4*)(pcon + dst * HIDDEN);
  const uint4* Qp = (const uint4*)(qh + r * HIDDEN);
  const uint4* Wp = (const uint4*)w2h;

  U4 s0, s1, d0, d1, q0, q1, w0, w1;
  s0.u = Sp[sub];     s1.u = Sp[sub + 4];
  d0.u = Dp[sub];     d1.u = Dp[sub + 4];
  q0.u = Qp[sub];     q1.u = Qp[sub + 4];
  w0.u = Wp[sub];     w1.u = Wp[sub + 4];
  const float sadd = ssrc[src] + sdst[dst] + srel[r];

  float acc = 0.f;
  #pragma unroll
  for (int j = 0; j < 4; ++j) {
    hv2 h0 = s0.h[j] + d0.h[j] + q0.h[j];
    h0 = __builtin_elementwise_max(h0, (hv2)(_Float16)0.f);
    acc = __builtin_amdgcn_fdot2(h0, w0.h[j], acc, false);
    hv2 h1 = s1.h[j] + d1.h[j] + q1.h[j];
    h1 = __builtin_elementwise_max(h1, (hv2)(_Float16)0.f);
    acc = __builtin_amdgcn_fdot2(h1, w1.h[j], acc, false);
  }
  acc += __shfl_xor(acc, 1);
  acc += __shfl_xor(acc, 2);

  if (sub == 0) {
    const float uu   = u[e];
    const float wsum = acc + sadd;
    const float eps  = fmaf(2.f * BIASF - 1.f, uu, 1.f - BIASF);   // eps
    const float ome  = fmaf(1.f - 2.f * BIASF, uu, BIASF);         // 1 - eps
    const float g    = __logf(eps) - __logf(ome);
    const float z    = (g + wsum) * (1.f / TEMPERATURE);
    out[e] = __builtin_amdgcn_rcpf(1.f + __expf(-z));
  }
}

extern "C" void kernel_launch(void* const* d_in, const int* in_sizes, int n_in,
                              void* d_out, int out_size, void* d_ws, size_t ws_size,
                              hipStream_t stream) {
  const int*   edge_index = (const int*)d_in[0];
  const int*   edge_type  = (const int*)d_in[1];
  const float* all_embed  = (const float*)d_in[2];
  const float* rel_emb    = (const float*)d_in[3];
  const float* u          = (const float*)d_in[4];
  const float* W1_src = (const float*)d_in[5];
  const float* b1_src = (const float*)d_in[6];
  const float* W2_src = (const float*)d_in[7];
  const float* b2_src = (const float*)d_in[8];
  const float* W1_dst = (const float*)d_in[9];
  const float* b1_dst = (const float*)d_in[10];
  const float* W2_dst = (const float*)d_in[11];
  const float* b2_dst = (const float*)d_in[12];
  const float* W1_edge = (const float*)d_in[13];
  const float* b1_edge = (const float*)d_in[14];
  const float* W2_edge = (const float*)d_in[15];
  const float* b2_edge = (const float*)d_in[16];
  const float* W1_con = (const float*)d_in[17];
  const float* b1_con = (const float*)d_in[18];
  const float* W2_con = (const float*)d_in[19];
  const float* b2_con = (const float*)d_in[20];

  // Workspace layout (all fp16 tables 16B-aligned):
  char* ws = (char*)d_ws;
  _Float16* pcon = (_Float16*)ws;                                 // 12,800,000 B
  float*    ssrc = (float*)(ws + (size_t)N_NODES * HIDDEN * 2);   // +400,000 B
  float*    sdst = ssrc + N_NODES;                                // +400,000 B
  _Float16* wt   = (_Float16*)(sdst + N_NODES);                   // 49,152 B (16B-aligned)
  _Float16* qh   = wt + 192 * NODE_DIM;                           // 6,400 B (16B-aligned)
  _Float16* w2h  = qh + N_RELS * HIDDEN;                          // 128 B (16B-aligned)
  float*    srel = (float*)(w2h + HIDDEN);                        // 200 B

  prep_small<<<96, 256, 0, stream>>>(W1_con, W1_src, W1_dst, wt);

  const int relblk = (N_RELS + 7) / 8;                 // 7
  prep_gemm<<<NBLK_GEMM + relblk, 512, 0, stream>>>(
      all_embed, wt,
      b1_src, W2_src, b2_src, b1_dst, W2_dst, b2_dst,
      rel_emb, W1_con, b1_con, W1_edge, b1_edge, W2_edge, b2_edge,
      b2_con, W2_con,
      (__half*)pcon, ssrc, sdst, qh, srel, w2h);

  edge_kernel<<<(N_EDGESC * 4) / 256, 256, 0, stream>>>(
      edge_index, edge_type, u, pcon, ssrc, sdst, qh, srel, w2h,
      (float*)d_out);
}